// Round 1
// 413.349 us; speedup vs baseline: 1.0145x; 1.0145x over previous
//
#include <hip/hip_runtime.h>
#include <math.h>

#define DIN  1024
#define DE   64
#define KK   8192
#define NN   512            // B*S flat rows
#define EPSF 1e-12f

// d_out layout (floats): decoded | perplexity | codebooks_used | indices
#define OUT_PERP   33554432
#define OUT_COUNTS 33554433
#define OUT_IDX    33562625

// ws layout (float offsets). Y aliases pooled (consumed by K2 before K4 writes Y).
#define WS_PPOOL 0            // pooled sums [512][1024] = 524,288 floats (pre 1/64 scale)
#define WS_Y     0            // [512][1024]    (aliases; K2 reads pool before K4 writes Y)
#define WS_CT    1048576      // [64][8192]     = 524,288
#define WS_WIT   1572864      // [1024][64]     = 65,536
#define WS_WOT   1638400      // [64][1024]     = 65,536
#define WS_F     1703936      // [512][64]      = 32,768
#define WS_FN    1736704      // [512]
#define WS_CBN   1737216      // [8192]
#define WS_MIN   1745408      // [512] u64 (= 1024 floats)

typedef unsigned long long ull;

// ---------------------------------------------------------------------------
// K1: blocks [0,2048): channel-split pooling. block = (n = bx>>2, q = bx&3).
//     Each block sums its DIN-quarter (256 ch = 64 float4) over all 64 pixels
//     of pool cell n and writes the FINAL pooled sum (no partials pass).
//     16-deep staged loads for MLP; 8 blocks/CU for occupancy.
//     blocks [2048,2080): codebook transpose CT[d][k] + cbn + WiT/WoT chunks
//     block 2080: zero counts, init minbuf
// ---------------------------------------------------------------------------
__global__ __launch_bounds__(256) void k_prep(
    const float* __restrict__ t0, const float* __restrict__ t1,
    const float* __restrict__ codebooks,
    const float* __restrict__ W_in, const float* __restrict__ W_out,
    float* __restrict__ ws, float* __restrict__ counts)
{
  int t = threadIdx.x;
  int bx = blockIdx.x;
  if (bx < 2048) {
    __shared__ float4 s_p[4][64];
    int n = bx >> 2, q = bx & 3;
    int b = n >> 4, gi = (n >> 2) & 3, gj = n & 3;
    int pg = t >> 6, ch = t & 63;     // wave pg: 2 pixel rows (16 px); lane ch: float4 channel
    size_t pix0 = (((size_t)b * 32 + gi * 8 + pg * 2) * 32) + gj * 8;  // pixel index
    const float4* p0 = (const float4*)t0 + pix0 * (DIN / 4) + q * 64 + ch;
    const float4* p1 = (const float4*)t1 + pix0 * (DIN / 4) + q * 64 + ch;
    float ax = 0.f, ay = 0.f, az = 0.f, aw = 0.f;
    #pragma unroll
    for (int half = 0; half < 2; ++half) {       // 2 pixel rows
      float4 u[8], v[8];
      #pragma unroll
      for (int i = 0; i < 8; ++i) {              // 8 cols: 16 loads issued back-to-back
        size_t off = ((size_t)half * 32 + i) * (DIN / 4);
        u[i] = p1[off];
        v[i] = p0[off];
      }
      #pragma unroll
      for (int i = 0; i < 8; ++i) {
        ax += u[i].x - v[i].x; ay += u[i].y - v[i].y;
        az += u[i].z - v[i].z; aw += u[i].w - v[i].w;
      }
    }
    s_p[pg][ch] = make_float4(ax, ay, az, aw);
    __syncthreads();
    if (t < 64) {
      float4 a0 = s_p[0][t], a1 = s_p[1][t], a2 = s_p[2][t], a3 = s_p[3][t];
      ((float4*)(ws + WS_PPOOL))[(size_t)n * (DIN / 4) + q * 64 + t] =
          make_float4(a0.x + a1.x + a2.x + a3.x,
                      a0.y + a1.y + a2.y + a3.y,
                      a0.z + a1.z + a2.z + a3.z,
                      a0.w + a1.w + a2.w + a3.w);
    }
    return;
  }
  if (bx < 2080) {
    int bb = bx - 2048;          // 0..31
    // codebook transpose + norms: thread t handles codebook k
    int k = bb * 256 + t;
    const float* row = codebooks + (size_t)k * DE;
    float* CT = ws + WS_CT;
    float s = 0.f;
    #pragma unroll 8
    for (int d = 0; d < DE; ++d) {
      float v = row[d];
      CT[(size_t)d * KK + k] = v;
      s = fmaf(v, v, s);
    }
    (ws + WS_CBN)[k] = s;
    // W_in / W_out transpose chunks (2048 elements per block each)
    float* WiT = ws + WS_WIT;
    float* WoT = ws + WS_WOT;
    #pragma unroll
    for (int i = 0; i < 8; ++i) {
      int f = bb * 2048 + i * 256 + t;
      float vi = W_in[f];
      int d = f >> 10, c = f & 1023;
      WiT[c * DE + d] = vi;                 // WiT[c][d]
      float vo = W_out[f];
      int c2 = f >> 6, d2 = f & 63;
      WoT[d2 * DIN + c2] = vo;              // WoT[d][c]
    }
    return;
  }
  // init block
  for (int i = t; i < KK; i += 256) counts[i] = 0.f;
  ull* mb = (ull*)(ws + WS_MIN);
  for (int i = t; i < NN; i += 256) mb[i] = ~0ull;
}

// ---------------------------------------------------------------------------
// K2: encode. block n: pooled row * (1/64) ; F[n][d] = dot + b_in
// ---------------------------------------------------------------------------
__global__ __launch_bounds__(256) void k_enc(
    const float* __restrict__ ws_ro, const float* __restrict__ b_in,
    float* __restrict__ ws)
{
  __shared__ float s_pool[DIN];
  __shared__ float s_part[4][DE];
  int t = threadIdx.x;
  int n = blockIdx.x;
  const float4* pool4 = (const float4*)(ws_ro + WS_PPOOL);
  float4 a = pool4[(size_t)n * (DIN / 4) + t];
  const float inv = 1.f / 64.f;
  ((float4*)s_pool)[t] = make_float4(a.x * inv, a.y * inv, a.z * inv, a.w * inv);
  __syncthreads();
  int w = t >> 6, lane = t & 63;
  const float* WiT = ws_ro + WS_WIT;
  float acc = 0.f;
  #pragma unroll 4
  for (int i = 0; i < 256; ++i) {
    float wv = WiT[(size_t)(w * 256 + i) * DE + lane];   // coalesced 256B/wave
    acc = fmaf(wv, s_pool[w * 256 + i], acc);            // LDS broadcast
  }
  s_part[w][lane] = acc;
  __syncthreads();
  if (t < DE) {
    float f = s_part[0][t] + s_part[1][t] + s_part[2][t] + s_part[3][t] + b_in[t];
    (ws + WS_F)[(size_t)n * DE + t] = f;
    float sq = f * f;
    #pragma unroll
    for (int m = 32; m > 0; m >>= 1) sq += __shfl_xor(sq, m, 64);
    if (t == 0) (ws + WS_FN)[n] = sq;
  }
}

// ---------------------------------------------------------------------------
// K3: distance scan. 1024 blocks = 128 rowgroups x 8 K-chunks.
//     thread: 4 codebooks (one float4 group along k), 4 rows -> 16 accums.
// ---------------------------------------------------------------------------
__device__ __forceinline__ void upd_min(ull& best, float e, int k) {
  e = fmaxf(e, 0.f);
  ull p = ((ull)__float_as_uint(e) << 32) | (unsigned int)k;
  best = (p < best) ? p : best;
}

__global__ __launch_bounds__(256) void k_dist(
    const float* __restrict__ ws_ro, float* __restrict__ ws)
{
  __shared__ float4 s_f4[4][16];
  __shared__ float s_fn[4];
  __shared__ ull s_min[4];
  int t = threadIdx.x;
  int rg = blockIdx.x & 127, kc = blockIdx.x >> 7;
  int n0 = rg * 4;
  if (t < 64) {
    int r = t >> 4, g = t & 15;
    s_f4[r][g] = ((const float4*)(ws_ro + WS_F + (size_t)(n0 + r) * DE))[g];
  }
  if (t < 4) { s_fn[t] = (ws_ro + WS_FN)[n0 + t]; s_min[t] = ~0ull; }
  __syncthreads();

  int kq = (kc << 8) + t;        // float4 group index along k: 0..2047
  int k0 = kq * 4;
  const float4* CT4 = (const float4*)(ws_ro + WS_CT);
  float4 acc0 = {0, 0, 0, 0}, acc1 = {0, 0, 0, 0}, acc2 = {0, 0, 0, 0}, acc3 = {0, 0, 0, 0};
  #pragma unroll 4
  for (int g = 0; g < 16; ++g) {
    float fa0[4], fa1[4], fa2[4], fa3[4];
    *(float4*)fa0 = s_f4[0][g];
    *(float4*)fa1 = s_f4[1][g];
    *(float4*)fa2 = s_f4[2][g];
    *(float4*)fa3 = s_f4[3][g];
    #pragma unroll
    for (int j = 0; j < 4; ++j) {
      float4 ct = CT4[(size_t)(4 * g + j) * (KK / 4) + kq];  // coalesced 1KB/wave
      acc0.x = fmaf(fa0[j], ct.x, acc0.x); acc0.y = fmaf(fa0[j], ct.y, acc0.y);
      acc0.z = fmaf(fa0[j], ct.z, acc0.z); acc0.w = fmaf(fa0[j], ct.w, acc0.w);
      acc1.x = fmaf(fa1[j], ct.x, acc1.x); acc1.y = fmaf(fa1[j], ct.y, acc1.y);
      acc1.z = fmaf(fa1[j], ct.z, acc1.z); acc1.w = fmaf(fa1[j], ct.w, acc1.w);
      acc2.x = fmaf(fa2[j], ct.x, acc2.x); acc2.y = fmaf(fa2[j], ct.y, acc2.y);
      acc2.z = fmaf(fa2[j], ct.z, acc2.z); acc2.w = fmaf(fa2[j], ct.w, acc2.w);
      acc3.x = fmaf(fa3[j], ct.x, acc3.x); acc3.y = fmaf(fa3[j], ct.y, acc3.y);
      acc3.z = fmaf(fa3[j], ct.z, acc3.z); acc3.w = fmaf(fa3[j], ct.w, acc3.w);
    }
  }
  float4 cn = ((const float4*)(ws_ro + WS_CBN))[kq];
  ull b0 = ~0ull, b1 = ~0ull, b2 = ~0ull, b3 = ~0ull;
  float fn0 = s_fn[0], fn1 = s_fn[1], fn2 = s_fn[2], fn3 = s_fn[3];
  upd_min(b0, fmaf(-2.f, acc0.x, fn0 + cn.x), k0);
  upd_min(b0, fmaf(-2.f, acc0.y, fn0 + cn.y), k0 + 1);
  upd_min(b0, fmaf(-2.f, acc0.z, fn0 + cn.z), k0 + 2);
  upd_min(b0, fmaf(-2.f, acc0.w, fn0 + cn.w), k0 + 3);
  upd_min(b1, fmaf(-2.f, acc1.x, fn1 + cn.x), k0);
  upd_min(b1, fmaf(-2.f, acc1.y, fn1 + cn.y), k0 + 1);
  upd_min(b1, fmaf(-2.f, acc1.z, fn1 + cn.z), k0 + 2);
  upd_min(b1, fmaf(-2.f, acc1.w, fn1 + cn.w), k0 + 3);
  upd_min(b2, fmaf(-2.f, acc2.x, fn2 + cn.x), k0);
  upd_min(b2, fmaf(-2.f, acc2.y, fn2 + cn.y), k0 + 1);
  upd_min(b2, fmaf(-2.f, acc2.z, fn2 + cn.z), k0 + 2);
  upd_min(b2, fmaf(-2.f, acc2.w, fn2 + cn.w), k0 + 3);
  upd_min(b3, fmaf(-2.f, acc3.x, fn3 + cn.x), k0);
  upd_min(b3, fmaf(-2.f, acc3.y, fn3 + cn.y), k0 + 1);
  upd_min(b3, fmaf(-2.f, acc3.z, fn3 + cn.z), k0 + 2);
  upd_min(b3, fmaf(-2.f, acc3.w, fn3 + cn.w), k0 + 3);
  atomicMin(&s_min[0], b0);
  atomicMin(&s_min[1], b1);
  atomicMin(&s_min[2], b2);
  atomicMin(&s_min[3], b3);
  __syncthreads();
  if (t < 4) atomicMin((ull*)(ws + WS_MIN) + n0 + t, s_min[t]);
}

// ---------------------------------------------------------------------------
// K4: NSVQ + project_out. block n: wave0 does NSVQ, all threads project.
// ---------------------------------------------------------------------------
__global__ __launch_bounds__(256) void k_nsvq_out(
    const float* __restrict__ ws_ro, const float* __restrict__ noise,
    const float* __restrict__ codebooks, const float* __restrict__ b_out,
    float* __restrict__ ws, float* __restrict__ counts,
    float* __restrict__ idx_out)
{
  __shared__ float s_q[DE];
  int t = threadIdx.x;
  int n = blockIdx.x;
  if (t < DE) {
    ull m = ((const ull*)(ws_ro + WS_MIN))[n];
    unsigned idx = (unsigned)(m & 0xffffffffu);
    float f = (ws_ro + WS_F)[(size_t)n * DE + t];
    float hv = codebooks[(size_t)idx * DE + t];
    float nz = noise[(size_t)n * DE + t];
    float df = f - hv;
    float sd = df * df, sn = nz * nz;
    #pragma unroll
    for (int m2 = 32; m2 > 0; m2 >>= 1) {
      sd += __shfl_xor(sd, m2, 64);
      sn += __shfl_xor(sn, m2, 64);
    }
    float scale = sqrtf(sd) / (sqrtf(sn) + EPSF);
    s_q[t] = fmaf(scale, nz, f);
    if (t == 0) {
      idx_out[n] = (float)idx;
      atomicAdd(&counts[idx], 1.0f);
    }
  }
  __syncthreads();
  const float4* WoT4 = (const float4*)(ws_ro + WS_WOT);
  float4 acc = {0, 0, 0, 0};
  #pragma unroll 4
  for (int i = 0; i < DE; ++i) {
    float q = s_q[i];
    float4 w = WoT4[(size_t)i * (DIN / 4) + t];   // coalesced
    acc.x = fmaf(q, w.x, acc.x); acc.y = fmaf(q, w.y, acc.y);
    acc.z = fmaf(q, w.z, acc.z); acc.w = fmaf(q, w.w, acc.w);
  }
  float4 bo = ((const float4*)b_out)[t];
  acc.x += bo.x; acc.y += bo.y; acc.z += bo.z; acc.w += bo.w;
  ((float4*)(ws + WS_Y))[(size_t)n * (DIN / 4) + t] = acc;
}

// ---------------------------------------------------------------------------
// K5: bilinear upsample + perplexity (block 1024)
// ---------------------------------------------------------------------------
__global__ __launch_bounds__(256) void k_decode(
    const float* __restrict__ ws_ro, const float* __restrict__ counts,
    float* __restrict__ decoded, float* __restrict__ perp)
{
  int t = threadIdx.x;
  if (blockIdx.x == 1024) {
    __shared__ float red[256];
    float s = 0.f;
    for (int k = t; k < KK; k += 256) {
      float p = counts[k] * (1.0f / 512.0f);
      s += p * logf(p + EPSF);
    }
    red[t] = s;
    __syncthreads();
    for (int o = 128; o > 0; o >>= 1) {
      if (t < o) red[t] += red[t + o];
      __syncthreads();
    }
    if (t == 0) perp[0] = expf(-red[0]);
    return;
  }
  __shared__ float s_y[8][DIN];  // rows {y0,y1} x gx{0..3} : 32 KB
  const float* Y = ws_ro + WS_Y;
  int bh = blockIdx.x;
  int b = bh >> 5, h = bh & 31;
  float sy = (h + 0.5f) * 0.125f - 0.5f;
  int y0 = (int)floorf(sy);
  float fy = sy - (float)y0;
  int y1 = min(y0 + 1, 3);
  y0 = max(y0, 0);
  #pragma unroll
  for (int gx = 0; gx < 4; ++gx) {
    ((float4*)s_y[gx])[t]     = ((const float4*)(Y + (size_t)(b * 16 + y0 * 4 + gx) * DIN))[t];
    ((float4*)s_y[4 + gx])[t] = ((const float4*)(Y + (size_t)(b * 16 + y1 * 4 + gx) * DIN))[t];
  }
  __syncthreads();
  float4* ob = (float4*)(decoded + (size_t)bh * (32 * DIN));
  for (int w = 0; w < 32; ++w) {
    float sx = (w + 0.5f) * 0.125f - 0.5f;
    int x0 = (int)floorf(sx);
    float fx = sx - (float)x0;
    int x1 = min(x0 + 1, 3);
    x0 = max(x0, 0);
    float w00 = (1.f - fy) * (1.f - fx), w01 = (1.f - fy) * fx;
    float w10 = fy * (1.f - fx), w11 = fy * fx;
    float4 v00 = ((const float4*)s_y[x0])[t];
    float4 v01 = ((const float4*)s_y[x1])[t];
    float4 v10 = ((const float4*)s_y[4 + x0])[t];
    float4 v11 = ((const float4*)s_y[4 + x1])[t];
    float4 o;
    o.x = w00 * v00.x + w01 * v01.x + w10 * v10.x + w11 * v11.x;
    o.y = w00 * v00.y + w01 * v01.y + w10 * v10.y + w11 * v11.y;
    o.z = w00 * v00.z + w01 * v01.z + w10 * v10.z + w11 * v11.z;
    o.w = w00 * v00.w + w01 * v01.w + w10 * v10.w + w11 * v11.w;
    ob[(size_t)w * (DIN / 4) + t] = o;
  }
}

extern "C" void kernel_launch(void* const* d_in, const int* in_sizes, int n_in,
                              void* d_out, int out_size, void* d_ws, size_t ws_size,
                              hipStream_t stream) {
  const float* t0        = (const float*)d_in[0];
  const float* t1        = (const float*)d_in[1];
  const float* noise     = (const float*)d_in[2];
  const float* codebooks = (const float*)d_in[3];
  const float* W_in      = (const float*)d_in[4];
  const float* b_in      = (const float*)d_in[5];
  const float* W_out     = (const float*)d_in[6];
  const float* b_out     = (const float*)d_in[7];
  float* out = (float*)d_out;
  float* ws  = (float*)d_ws;

  float* decoded = out;
  float* perp    = out + OUT_PERP;
  float* counts  = out + OUT_COUNTS;
  float* idx_out = out + OUT_IDX;

  hipLaunchKernelGGL(k_prep, dim3(2081), dim3(256), 0, stream,
                     t0, t1, codebooks, W_in, W_out, ws, counts);
  hipLaunchKernelGGL(k_enc, dim3(512), dim3(256), 0, stream,
                     ws, b_in, ws);
  hipLaunchKernelGGL(k_dist, dim3(1024), dim3(256), 0, stream,
                     ws, ws);
  hipLaunchKernelGGL(k_nsvq_out, dim3(512), dim3(256), 0, stream,
                     ws, noise, codebooks, b_out, ws, counts, idx_out);
  hipLaunchKernelGGL(k_decode, dim3(1025), dim3(256), 0, stream,
                     ws, counts, decoded, perp);
}